// Round 1
// baseline (733.173 us; speedup 1.0000x reference)
//
#include <hip/hip_runtime.h>
#include <hip/hip_bf16.h>
#include <stdint.h>
#include <stddef.h>

// ---------------- problem constants ----------------
#define B_TOT   2048        // windows total
#define NTOK    49          // tokens per window
#define CDIM    512
#define NHEAD   16
#define HD      32
#define NWIN    64          // windows per image
#define MROWS   (B_TOT*NTOK)   // 100352
#define O_QKV   1536
#define SCALE_F 0.17677669529663687f   // 32^-0.5

typedef short bf16x8 __attribute__((ext_vector_type(8)));
typedef float f32x4  __attribute__((ext_vector_type(4)));

__device__ __forceinline__ unsigned short f2bf(float f){
  union { float f; unsigned u; } v; v.f = f;
  unsigned r = v.u + 0x7fffu + ((v.u >> 16) & 1u);
  return (unsigned short)(r >> 16);
}

__device__ __forceinline__ void gl_lds16(const void* g, void* l){
  __builtin_amdgcn_global_load_lds(
      (const __attribute__((address_space(1))) unsigned int*)g,
      (__attribute__((address_space(3))) unsigned int*)l, 16, 0, 0);
}

// ---------------- kernel 1: x fp32 -> bf16 ----------------
__global__ void k_cvt_x(const float* __restrict__ x, unsigned short* __restrict__ xb, int n4){
  int i = blockIdx.x * blockDim.x + threadIdx.x;
  int st = gridDim.x * blockDim.x;
  for (; i < n4; i += st){
    float4 v = ((const float4*)x)[i];
    uint2 o;
    o.x = (unsigned)f2bf(v.x) | ((unsigned)f2bf(v.y) << 16);
    o.y = (unsigned)f2bf(v.z) | ((unsigned)f2bf(v.w) << 16);
    ((uint2*)xb)[i] = o;
  }
}

// ---------------- kernel 2: weights -> bf16, fused bias+mask table ----------------
__global__ void k_prep(const float* __restrict__ qkv_w, const float* __restrict__ proj_w,
                       const float* __restrict__ rpb, const int* __restrict__ rel_idx,
                       const float* __restrict__ mask,
                       unsigned short* __restrict__ wqkv, unsigned short* __restrict__ wproj,
                       float* __restrict__ bmb){
  int i = blockIdx.x * blockDim.x + threadIdx.x;
  int st = gridDim.x * blockDim.x;
  for (int j = i; j < O_QKV*CDIM; j += st) wqkv[j] = f2bf(qkv_w[j]);
  for (int j = i; j < CDIM*CDIM;  j += st) wproj[j] = f2bf(proj_w[j]);
  // bmb[(wi*16+h)*2401 + rc] = mask[wi][rc] + rpb[rel_idx[rc]][h]
  const int TOT = NWIN * NHEAD * NTOK * NTOK;
  for (int j = i; j < TOT; j += st){
    int wi = j / (NHEAD * NTOK * NTOK);
    int t  = j - wi * (NHEAD * NTOK * NTOK);
    int h  = t / (NTOK * NTOK);
    int rc = t - h * (NTOK * NTOK);
    bmb[j] = mask[wi * (NTOK*NTOK) + rc] + rpb[rel_idx[rc] * NHEAD + h];
  }
}

// ---------------- GEMM: C[M,N] = A[M,K] * B[N,K]^T + bias ----------------
// A,B bf16 row-major (K contiguous). OUT_F32: 1 -> float out, 0 -> bf16 out.
// Tile 128x128, BK=64, 256 threads (4 waves, 2x2), each wave 64x64 (4x4 MFMA frags).
template<int OUT_F32>
__global__ __launch_bounds__(256) void k_gemm_bt(const unsigned short* __restrict__ Ag,
                                                 const unsigned short* __restrict__ Bg,
                                                 const float* __restrict__ bias,
                                                 void* __restrict__ Cout,
                                                 int Ndim, int Kdim){
  __shared__ unsigned short LA[128*64];
  __shared__ unsigned short LB[128*64];
  const int tid = threadIdx.x;
  const int wv = tid >> 6, lane = tid & 63, lg = lane >> 4, lr = lane & 15;
  const int wm = wv >> 1, wn = wv & 1;
  const int bm0 = blockIdx.y * 128, bn0 = blockIdx.x * 128;
  const size_t Kb = (size_t)Kdim * 2;   // row stride bytes

  f32x4 acc[4][4];
  #pragma unroll
  for (int mi = 0; mi < 4; ++mi)
    #pragma unroll
    for (int ni = 0; ni < 4; ++ni)
      #pragma unroll
      for (int r = 0; r < 4; ++r) acc[mi][ni][r] = 0.f;

  for (int k0 = 0; k0 < Kdim; k0 += 64){
    #pragma unroll
    for (int i = 0; i < 4; ++i){
      int chunk = i * 4 + wv;                 // 16 chunks of 1KB per 16KB tile
      int o = chunk * 1024 + lane * 16;
      int row = o >> 7, cb = o & 127;         // 128 bytes per row (BK=64 bf16)
      gl_lds16((const char*)Ag + (size_t)(bm0 + row) * Kb + (size_t)k0 * 2 + cb,
               (char*)LA + chunk * 1024);
      gl_lds16((const char*)Bg + (size_t)(bn0 + row) * Kb + (size_t)k0 * 2 + cb,
               (char*)LB + chunk * 1024);
    }
    __syncthreads();

    bf16x8 a[4][2], b[4][2];
    #pragma unroll
    for (int mi = 0; mi < 4; ++mi)
      #pragma unroll
      for (int s = 0; s < 2; ++s)
        a[mi][s] = *(const bf16x8*)&LA[(wm*64 + mi*16 + lr) * 64 + s*32 + lg*8];
    #pragma unroll
    for (int ni = 0; ni < 4; ++ni)
      #pragma unroll
      for (int s = 0; s < 2; ++s)
        b[ni][s] = *(const bf16x8*)&LB[(wn*64 + ni*16 + lr) * 64 + s*32 + lg*8];

    #pragma unroll
    for (int s = 0; s < 2; ++s)
      #pragma unroll
      for (int mi = 0; mi < 4; ++mi)
        #pragma unroll
        for (int ni = 0; ni < 4; ++ni)
          acc[mi][ni] = __builtin_amdgcn_mfma_f32_16x16x32_bf16(a[mi][s], b[ni][s], acc[mi][ni], 0, 0, 0);

    __syncthreads();
  }

  // epilogue: C row = (lg*4 + r), col = lr within each 16x16 tile
  #pragma unroll
  for (int mi = 0; mi < 4; ++mi)
    #pragma unroll
    for (int ni = 0; ni < 4; ++ni)
      #pragma unroll
      for (int r = 0; r < 4; ++r){
        int row = bm0 + wm*64 + mi*16 + lg*4 + r;
        int col = bn0 + wn*64 + ni*16 + lr;
        float v = acc[mi][ni][r] + bias[col];
        if (OUT_F32) ((float*)Cout)[(size_t)row * Ndim + col] = v;
        else ((unsigned short*)Cout)[(size_t)row * Ndim + col] = f2bf(v);
      }
}

// ---------------- attention: one wave per (window, head) ----------------
// qkv row-major [MROWS][1536]; q at col h*32, k at 512+h*32, v at 1024+h*32.
__global__ __launch_bounds__(256) void k_attn(const unsigned short* __restrict__ qkv,
                                              const float* __restrict__ bm,
                                              unsigned short* __restrict__ ao){
  __shared__ unsigned short P[4][64*64];   // per-wave P tile (bf16, swizzled)
  const int wv = threadIdx.x >> 6, lane = threadIdx.x & 63;
  const int lg = lane >> 4, lr = lane & 15;
  const int gw = blockIdx.x * 4 + wv;      // global wave id
  const int w = gw >> 4, h = gw & 15, wi = w & (NWIN - 1);

  bf16x8 zf; f32x4 z4;
  #pragma unroll
  for (int j = 0; j < 8; ++j) zf[j] = 0;
  #pragma unroll
  for (int j = 0; j < 4; ++j) z4[j] = 0.f;

  const unsigned short* qb = qkv + (size_t)w * NTOK * O_QKV + h * HD;

  // --- QK^T ---
  bf16x8 qf[4], kf[4];
  #pragma unroll
  for (int mi = 0; mi < 4; ++mi){
    int t = mi*16 + lr;
    qf[mi] = (t < NTOK) ? *(const bf16x8*)(qb + (size_t)t * O_QKV + lg*8) : zf;
    kf[mi] = (t < NTOK) ? *(const bf16x8*)(qb + 512 + (size_t)t * O_QKV + lg*8) : zf;
  }
  f32x4 s[4][4];
  #pragma unroll
  for (int mi = 0; mi < 4; ++mi)
    #pragma unroll
    for (int ni = 0; ni < 4; ++ni)
      s[mi][ni] = __builtin_amdgcn_mfma_f32_16x16x32_bf16(qf[mi], kf[ni], z4, 0, 0, 0);

  // --- scale + bias + mask + softmax (unnormalized P, row sums kept) ---
  const float* bmp = bm + (size_t)(wi * NHEAD + h) * (NTOK * NTOK);
  float rs[4][4];
  #pragma unroll
  for (int mi = 0; mi < 4; ++mi){
    #pragma unroll
    for (int r = 0; r < 4; ++r){
      int row = mi*16 + lg*4 + r;
      float v[4];
      #pragma unroll
      for (int ni = 0; ni < 4; ++ni){
        int col = ni*16 + lr;
        float t = s[mi][ni][r] * SCALE_F;
        if (row < NTOK && col < NTOK) t += bmp[row * NTOK + col];
        if (col >= NTOK) t = -1e30f;
        v[ni] = t;
      }
      float mx = fmaxf(fmaxf(v[0], v[1]), fmaxf(v[2], v[3]));
      mx = fmaxf(mx, __shfl_xor(mx, 1));
      mx = fmaxf(mx, __shfl_xor(mx, 2));
      mx = fmaxf(mx, __shfl_xor(mx, 4));
      mx = fmaxf(mx, __shfl_xor(mx, 8));
      float sum = 0.f;
      #pragma unroll
      for (int ni = 0; ni < 4; ++ni){
        float p = __expf(v[ni] - mx);
        sum += p;
        s[mi][ni][r] = p;
      }
      sum += __shfl_xor(sum, 1);
      sum += __shfl_xor(sum, 2);
      sum += __shfl_xor(sum, 4);
      sum += __shfl_xor(sum, 8);
      rs[mi][r] = sum;
    }
  }

  // --- write P (bf16) to swizzled LDS: byte = row*128 + col*2, ^= (row&7)<<4 ---
  char* Pb = (char*)P[wv];
  #pragma unroll
  for (int mi = 0; mi < 4; ++mi)
    #pragma unroll
    for (int ni = 0; ni < 4; ++ni)
      #pragma unroll
      for (int r = 0; r < 4; ++r){
        int row = mi*16 + lg*4 + r, col = ni*16 + lr;
        int byte = (row << 7) + (col << 1);
        byte ^= (row & 7) << 4;
        *(unsigned short*)(Pb + byte) = f2bf(s[mi][ni][r]);
      }

  // --- PV ---
  const unsigned short* vb = qkv + (size_t)w * NTOK * O_QKV + 1024 + h * HD;
  f32x4 o[4][2];
  #pragma unroll
  for (int mi = 0; mi < 4; ++mi)
    #pragma unroll
    for (int ni = 0; ni < 2; ++ni)
      #pragma unroll
      for (int r = 0; r < 4; ++r) o[mi][ni][r] = 0.f;

  #pragma unroll
  for (int ss = 0; ss < 2; ++ss){
    bf16x8 vf[2];
    #pragma unroll
    for (int ni = 0; ni < 2; ++ni)
      #pragma unroll
      for (int j = 0; j < 8; ++j){
        int t = ss*32 + lg*8 + j;
        vf[ni][j] = (t < NTOK) ? (short)vb[(size_t)t * O_QKV + ni*16 + lr] : (short)0;
      }
    #pragma unroll
    for (int mi = 0; mi < 4; ++mi){
      int row = mi*16 + lr;
      int byte = (row << 7) + ((ss*64 + lg*16) ^ ((row & 7) << 4));
      bf16x8 pf = *(const bf16x8*)(Pb + byte);
      #pragma unroll
      for (int ni = 0; ni < 2; ++ni)
        o[mi][ni] = __builtin_amdgcn_mfma_f32_16x16x32_bf16(pf, vf[ni], o[mi][ni], 0, 0, 0);
    }
  }

  // --- normalize + store attention output (bf16) ---
  unsigned short* aop = ao + (size_t)w * NTOK * CDIM + h * HD;
  #pragma unroll
  for (int mi = 0; mi < 4; ++mi)
    #pragma unroll
    for (int ni = 0; ni < 2; ++ni)
      #pragma unroll
      for (int r = 0; r < 4; ++r){
        int row = mi*16 + lg*4 + r, col = ni*16 + lr;
        if (row < NTOK)
          aop[(size_t)row * CDIM + col] = f2bf(o[mi][ni][r] / rs[mi][r]);
      }
}

// ---------------- launcher ----------------
extern "C" void kernel_launch(void* const* d_in, const int* in_sizes, int n_in,
                              void* d_out, int out_size, void* d_ws, size_t ws_size,
                              hipStream_t stream){
  const float* x      = (const float*)d_in[0];
  const float* mask   = (const float*)d_in[1];
  const float* qkv_w  = (const float*)d_in[2];
  const float* qkv_b  = (const float*)d_in[3];
  const float* proj_w = (const float*)d_in[4];
  const float* proj_b = (const float*)d_in[5];
  const float* rpb    = (const float*)d_in[6];
  const int*   rel_i  = (const int*)d_in[7];

  char* ws = (char*)d_ws;
  // layout (bytes):
  //   xb    @ 0          : 100352*512*2  = 102,760,448   (reused as attention out)
  //   qkvb  @ 102760448  : 100352*1536*2 = 308,281,344
  //   wqkv  @ 411041792  : 1536*512*2    = 1,572,864
  //   wproj @ 412614656  : 512*512*2     = 524,288
  //   bmb   @ 413138944  : 64*16*49*49*4 = 9,834,496     -> total 422,973,440
  unsigned short* xb    = (unsigned short*)(ws);
  unsigned short* qkvb  = (unsigned short*)(ws + 102760448);
  unsigned short* wqkv  = (unsigned short*)(ws + 411041792);
  unsigned short* wproj = (unsigned short*)(ws + 412614656);
  float*          bmb   = (float*)(ws + 413138944);

  // 1) x -> bf16
  k_cvt_x<<<2048, 256, 0, stream>>>(x, xb, MROWS * CDIM / 4);
  // 2) weights -> bf16 + bias/mask table
  k_prep<<<512, 256, 0, stream>>>(qkv_w, proj_w, rpb, rel_i, mask, wqkv, wproj, bmb);
  // 3) QKV GEMM: [100352,1536] = xb * wqkv^T + qkv_b   (bf16 out)
  k_gemm_bt<0><<<dim3(O_QKV/128, MROWS/128), 256, 0, stream>>>(xb, wqkv, qkv_b, qkvb, O_QKV, CDIM);
  // 4) attention (writes bf16 attn-out into xb region)
  k_attn<<<(B_TOT * NHEAD) / 4, 256, 0, stream>>>(qkvb, bmb, xb);
  // 5) proj GEMM: out[100352,512] = xb * wproj^T + proj_b (f32 out)
  k_gemm_bt<1><<<dim3(CDIM/128, MROWS/128), 256, 0, stream>>>(xb, wproj, proj_b, d_out, CDIM, CDIM);
}

// Round 2
// 587.023 us; speedup vs baseline: 1.2490x; 1.2490x over previous
//
#include <hip/hip_runtime.h>
#include <hip/hip_bf16.h>
#include <stdint.h>
#include <stddef.h>

// ---------------- problem constants ----------------
#define B_TOT   2048        // windows total
#define NTOK    49          // tokens per window
#define CDIM    512
#define NHEAD   16
#define HD      32
#define NWIN    64          // windows per image
#define MROWS   (B_TOT*NTOK)   // 100352
#define O_QKV   1536
#define SCALE_F 0.17677669529663687f   // 32^-0.5

typedef short bf16x8 __attribute__((ext_vector_type(8)));
typedef float f32x4  __attribute__((ext_vector_type(4)));

__device__ __forceinline__ unsigned short f2bf(float f){
  union { float f; unsigned u; } v; v.f = f;
  unsigned r = v.u + 0x7fffu + ((v.u >> 16) & 1u);
  return (unsigned short)(r >> 16);
}

#define GL16(g,l) __builtin_amdgcn_global_load_lds( \
      (const __attribute__((address_space(1))) unsigned int*)(g), \
      (__attribute__((address_space(3))) unsigned int*)(l), 16, 0, 0)

// ---------------- kernel 1: x fp32 -> bf16 ----------------
__global__ void k_cvt_x(const float* __restrict__ x, unsigned short* __restrict__ xb, int n4){
  int i = blockIdx.x * blockDim.x + threadIdx.x;
  int st = gridDim.x * blockDim.x;
  for (; i < n4; i += st){
    float4 v = ((const float4*)x)[i];
    uint2 o;
    o.x = (unsigned)f2bf(v.x) | ((unsigned)f2bf(v.y) << 16);
    o.y = (unsigned)f2bf(v.z) | ((unsigned)f2bf(v.w) << 16);
    ((uint2*)xb)[i] = o;
  }
}

// ---------------- kernel 2: weights -> bf16, fused bias+mask table ----------------
__global__ void k_prep(const float* __restrict__ qkv_w, const float* __restrict__ proj_w,
                       const float* __restrict__ rpb, const int* __restrict__ rel_idx,
                       const float* __restrict__ mask,
                       unsigned short* __restrict__ wqkv, unsigned short* __restrict__ wproj,
                       float* __restrict__ bmb){
  int i = blockIdx.x * blockDim.x + threadIdx.x;
  int st = gridDim.x * blockDim.x;
  for (int j = i; j < O_QKV*CDIM; j += st) wqkv[j] = f2bf(qkv_w[j]);
  for (int j = i; j < CDIM*CDIM;  j += st) wproj[j] = f2bf(proj_w[j]);
  const int TOT = NWIN * NHEAD * NTOK * NTOK;
  for (int j = i; j < TOT; j += st){
    int wi = j / (NHEAD * NTOK * NTOK);
    int t  = j - wi * (NHEAD * NTOK * NTOK);
    int h  = t / (NTOK * NTOK);
    int rc = t - h * (NTOK * NTOK);
    bmb[j] = mask[wi * (NTOK*NTOK) + rc] + rpb[rel_idx[rc] * NHEAD + h];
  }
}

// ---------------- 8-phase 256x256 GEMM: C[M,N] = A[M,K]*B[N,K]^T + bias ----------------
// 512 threads = 8 waves (2 M x 4 N). BK=64, double-buffered (2 K-tiles in LDS).
// LDS 128 KiB: A buffers [2][256r][64c] bf16 @0, B buffers @65536.
// LDS row layout: A: row = rg*128 + wm*64 + r  (global row bm0 + wm*128 + rg*64 + r)
//                 B: row = cg*128 + wn*32 + rr (global col bn0 + wn*64 + cg*32 + rr)
// Swizzle (both sides, involution): byte ^= ((row&7)<<4).
// Phase ds-loads reuse operand regs across phases: 12/4/8/4 reads per phase.
// vmcnt(4) only at phases 4 and 8 (2 half-tiles = 4 loads allowed in flight).

#define LDA_(P,RG,MI,S) (*(const bf16x8*)(rA + (P)*32768 + (RG)*16384 + (MI)*2048 + ((S)?(cb0^64):cb0)))
#define LDB_(P,CG,NI,S) (*(const bf16x8*)(rB + (P)*32768 + (CG)*16384 + (NI)*2048 + ((S)?(cb0^64):cb0)))

#define STAGE_A(P,HG,KT) { \
    GL16(aS0 + (size_t)(HG)*64*Kb + (size_t)(KT)*128, ldA + (P)*32768 + (HG)*16384); \
    GL16(aS1 + (size_t)(HG)*64*Kb + (size_t)(KT)*128, ldA + (P)*32768 + (HG)*16384 + 8192); }
#define STAGE_B(P,HG,KT) { \
    GL16(bS0 + (size_t)(HG)*32*Kb + (size_t)(KT)*128, ldB + (P)*32768 + (HG)*16384); \
    GL16(bS1 + (size_t)(HG)*32*Kb + (size_t)(KT)*128, ldB + (P)*32768 + (HG)*16384 + 8192); }

#define PHASE(P,RG,CG,DOA,DOB,VM,...) { \
  if (DOA){ _Pragma("unroll") for (int mi=0;mi<4;++mi){ af[mi][0]=LDA_(P,RG,mi,0); af[mi][1]=LDA_(P,RG,mi,1);} } \
  if (DOB){ _Pragma("unroll") for (int ni=0;ni<2;++ni){ bf_[ni][0]=LDB_(P,CG,ni,0); bf_[ni][1]=LDB_(P,CG,ni,1);} } \
  __VA_ARGS__; \
  __builtin_amdgcn_s_barrier(); \
  asm volatile("s_waitcnt lgkmcnt(0)" ::: "memory"); \
  __builtin_amdgcn_sched_barrier(0); \
  __builtin_amdgcn_s_setprio(1); \
  _Pragma("unroll") for (int s=0;s<2;++s) \
    _Pragma("unroll") for (int mi=0;mi<4;++mi) \
      _Pragma("unroll") for (int ni=0;ni<2;++ni) \
        acc[(RG)*4+mi][(CG)*2+ni] = __builtin_amdgcn_mfma_f32_16x16x32_bf16(af[mi][s], bf_[ni][s], acc[(RG)*4+mi][(CG)*2+ni], 0,0,0); \
  __builtin_amdgcn_s_setprio(0); \
  if (VM) asm volatile("s_waitcnt vmcnt(4)" ::: "memory"); \
  __builtin_amdgcn_s_barrier(); \
  asm volatile("" ::: "memory"); \
}

template<int OUT_F32>
__global__ __launch_bounds__(512, 2) void k_gemm8(const unsigned short* __restrict__ Ag,
                                                  const unsigned short* __restrict__ Bg,
                                                  const float* __restrict__ bias,
                                                  void* __restrict__ Cout,
                                                  int Ndim, int Kdim){
  extern __shared__ char smem[];
  const int tid = threadIdx.x;
  const int wv = tid >> 6, lane = tid & 63, lg = lane >> 4, lr = lane & 15;
  const int wm = wv >> 2, wn = wv & 3;

  // bijective XCD-aware block swizzle (nwg % 8 == 0 for both GEMMs)
  const int nbx = gridDim.x;
  const int nwg = nbx * gridDim.y;
  const int id  = blockIdx.y * nbx + blockIdx.x;
  const int nid = (id & 7) * (nwg >> 3) + (id >> 3);
  const int bx = nid % nbx, by = nid / nbx;
  const int bm0 = by * 256, bn0 = bx * 256;
  const size_t Kb = (size_t)Kdim * 2;
  const int NIT = Kdim >> 7;   // two K-tiles (BK=64) per iteration

  // staging source addressing (pre-swizzled global source, linear LDS dest)
  const int srow = tid >> 3;                                  // 0..63
  const int scb  = ((tid & 7) << 4) ^ ((srow & 7) << 4);
  const char* aS0 = (const char*)Ag + (size_t)(bm0 + srow) * Kb + scb;
  const char* aS1 = (const char*)Ag + (size_t)(bm0 + 128 + srow) * Kb + scb;
  const char* bS0 = (const char*)Bg + (size_t)(bn0 + (srow>>5)*64 + (srow&31)) * Kb + scb;
  const char* bS1 = (const char*)Bg + (size_t)(bn0 + 128 + (srow>>5)*64 + (srow&31)) * Kb + scb;
  char* ldA = smem + wv * 1024;
  char* ldB = smem + 65536 + wv * 1024;

  // read addressing (swizzled)
  const int cb0 = (lg * 16) ^ ((lr & 7) << 4);
  const char* rA = smem + (wm*64 + lr) * 128;
  const char* rB = smem + 65536 + (wn*32 + lr) * 128;

  f32x4 acc[8][4];
  #pragma unroll
  for (int i = 0; i < 8; ++i)
    #pragma unroll
    for (int j = 0; j < 4; ++j)
      #pragma unroll
      for (int r = 0; r < 4; ++r) acc[i][j][r] = 0.f;

  bf16x8 af[4][2], bf_[2][2];

  // prologue: buf0 = tile0 (all 4 halves), buf1 = tile1 (A-rg0, B-cg1)
  STAGE_A(0,0,0); STAGE_A(0,1,0); STAGE_B(0,0,0); STAGE_B(0,1,0);
  STAGE_A(1,0,1); STAGE_B(1,1,1);
  asm volatile("s_waitcnt vmcnt(4)" ::: "memory");
  __builtin_amdgcn_s_barrier();
  asm volatile("" ::: "memory");

  for (int it = 0; it < NIT; ++it){
    const int T = 2*it;
    PHASE(0, 0,0, 1,1, 0, STAGE_A(1,1,(T+1)))   // quad(0,0) buf0 | stage buf1.A.rg1 <- T+1
    PHASE(0, 0,1, 0,1, 0, STAGE_B(1,0,(T+1)))   // quad(0,1)      | stage buf1.B.cg0 <- T+1
    PHASE(0, 1,1, 1,0, 0, STAGE_A(0,0,(T+2)))   // quad(1,1)      | stage buf0.A.rg0 <- T+2
    PHASE(0, 1,0, 0,1, 1, STAGE_B(0,1,(T+2)))   // quad(1,0)      | stage buf0.B.cg1 <- T+2 | vmcnt(4)
    PHASE(1, 0,0, 1,1, 0, STAGE_A(0,1,(T+2)))   // quad(0,0) buf1 | stage buf0.A.rg1 <- T+2
    PHASE(1, 0,1, 0,1, 0, STAGE_B(0,0,(T+2)))   // quad(0,1)      | stage buf0.B.cg0 <- T+2
    PHASE(1, 1,1, 1,0, 0, STAGE_A(1,0,(T+3)))   // quad(1,1)      | stage buf1.A.rg0 <- T+3
    PHASE(1, 1,0, 0,1, 1, STAGE_B(1,1,(T+3)))   // quad(1,0)      | stage buf1.B.cg1 <- T+3 | vmcnt(4)
  }

  // epilogue
  #pragma unroll
  for (int RG = 0; RG < 2; ++RG)
    #pragma unroll
    for (int mi = 0; mi < 4; ++mi)
      #pragma unroll
      for (int CG = 0; CG < 2; ++CG)
        #pragma unroll
        for (int ni = 0; ni < 2; ++ni){
          f32x4 v = acc[RG*4+mi][CG*2+ni];
          const int col = bn0 + wn*64 + CG*32 + ni*16 + lr;
          const float bc = bias[col];
          #pragma unroll
          for (int r = 0; r < 4; ++r){
            const int row = bm0 + wm*128 + RG*64 + mi*16 + lg*4 + r;
            const float t = v[r] + bc;
            if (OUT_F32) ((float*)Cout)[(size_t)row * Ndim + col] = t;
            else ((unsigned short*)Cout)[(size_t)row * Ndim + col] = f2bf(t);
          }
        }
}

// ---------------- attention: one wave per (window, head) ----------------
__global__ __launch_bounds__(256) void k_attn(const unsigned short* __restrict__ qkv,
                                              const float* __restrict__ bm,
                                              unsigned short* __restrict__ ao){
  __shared__ unsigned short P[4][64*64];
  const int wv = threadIdx.x >> 6, lane = threadIdx.x & 63;
  const int lg = lane >> 4, lr = lane & 15;
  const int gw = blockIdx.x * 4 + wv;
  const int w = gw >> 4, h = gw & 15, wi = w & (NWIN - 1);

  bf16x8 zf; f32x4 z4;
  #pragma unroll
  for (int j = 0; j < 8; ++j) zf[j] = 0;
  #pragma unroll
  for (int j = 0; j < 4; ++j) z4[j] = 0.f;

  const unsigned short* qb = qkv + (size_t)w * NTOK * O_QKV + h * HD;

  bf16x8 qf[4], kf[4];
  #pragma unroll
  for (int mi = 0; mi < 4; ++mi){
    int t = mi*16 + lr;
    qf[mi] = (t < NTOK) ? *(const bf16x8*)(qb + (size_t)t * O_QKV + lg*8) : zf;
    kf[mi] = (t < NTOK) ? *(const bf16x8*)(qb + 512 + (size_t)t * O_QKV + lg*8) : zf;
  }
  f32x4 s[4][4];
  #pragma unroll
  for (int mi = 0; mi < 4; ++mi)
    #pragma unroll
    for (int ni = 0; ni < 4; ++ni)
      s[mi][ni] = __builtin_amdgcn_mfma_f32_16x16x32_bf16(qf[mi], kf[ni], z4, 0, 0, 0);

  const float* bmp = bm + (size_t)(wi * NHEAD + h) * (NTOK * NTOK);
  float rs[4][4];
  #pragma unroll
  for (int mi = 0; mi < 4; ++mi){
    #pragma unroll
    for (int r = 0; r < 4; ++r){
      int row = mi*16 + lg*4 + r;
      float v[4];
      #pragma unroll
      for (int ni = 0; ni < 4; ++ni){
        int col = ni*16 + lr;
        float t = s[mi][ni][r] * SCALE_F;
        if (row < NTOK && col < NTOK) t += bmp[row * NTOK + col];
        if (col >= NTOK) t = -1e30f;
        v[ni] = t;
      }
      float mx = fmaxf(fmaxf(v[0], v[1]), fmaxf(v[2], v[3]));
      mx = fmaxf(mx, __shfl_xor(mx, 1));
      mx = fmaxf(mx, __shfl_xor(mx, 2));
      mx = fmaxf(mx, __shfl_xor(mx, 4));
      mx = fmaxf(mx, __shfl_xor(mx, 8));
      float sum = 0.f;
      #pragma unroll
      for (int ni = 0; ni < 4; ++ni){
        float p = __expf(v[ni] - mx);
        sum += p;
        s[mi][ni][r] = p;
      }
      sum += __shfl_xor(sum, 1);
      sum += __shfl_xor(sum, 2);
      sum += __shfl_xor(sum, 4);
      sum += __shfl_xor(sum, 8);
      rs[mi][r] = sum;
    }
  }

  char* Pb = (char*)P[wv];
  #pragma unroll
  for (int mi = 0; mi < 4; ++mi)
    #pragma unroll
    for (int ni = 0; ni < 4; ++ni)
      #pragma unroll
      for (int r = 0; r < 4; ++r){
        int row = mi*16 + lg*4 + r, col = ni*16 + lr;
        int byte = (row << 7) + (col << 1);
        byte ^= (row & 7) << 4;
        *(unsigned short*)(Pb + byte) = f2bf(s[mi][ni][r]);
      }

  const unsigned short* vb = qkv + (size_t)w * NTOK * O_QKV + 1024 + h * HD;
  f32x4 o[4][2];
  #pragma unroll
  for (int mi = 0; mi < 4; ++mi)
    #pragma unroll
    for (int ni = 0; ni < 2; ++ni)
      #pragma unroll
      for (int r = 0; r < 4; ++r) o[mi][ni][r] = 0.f;

  #pragma unroll
  for (int ss = 0; ss < 2; ++ss){
    bf16x8 vf[2];
    #pragma unroll
    for (int ni = 0; ni < 2; ++ni)
      #pragma unroll
      for (int j = 0; j < 8; ++j){
        int t = ss*32 + lg*8 + j;
        vf[ni][j] = (t < NTOK) ? (short)vb[(size_t)t * O_QKV + ni*16 + lr] : (short)0;
      }
    #pragma unroll
    for (int mi = 0; mi < 4; ++mi){
      int row = mi*16 + lr;
      int byte = (row << 7) + ((ss*64 + lg*16) ^ ((row & 7) << 4));
      bf16x8 pf = *(const bf16x8*)(Pb + byte);
      #pragma unroll
      for (int ni = 0; ni < 2; ++ni)
        o[mi][ni] = __builtin_amdgcn_mfma_f32_16x16x32_bf16(pf, vf[ni], o[mi][ni], 0, 0, 0);
    }
  }

  unsigned short* aop = ao + (size_t)w * NTOK * CDIM + h * HD;
  #pragma unroll
  for (int mi = 0; mi < 4; ++mi)
    #pragma unroll
    for (int ni = 0; ni < 2; ++ni)
      #pragma unroll
      for (int r = 0; r < 4; ++r){
        int row = mi*16 + lg*4 + r, col = ni*16 + lr;
        if (row < NTOK)
          aop[(size_t)row * CDIM + col] = f2bf(o[mi][ni][r] / rs[mi][r]);
      }
}

// ---------------- launcher ----------------
extern "C" void kernel_launch(void* const* d_in, const int* in_sizes, int n_in,
                              void* d_out, int out_size, void* d_ws, size_t ws_size,
                              hipStream_t stream){
  const float* x      = (const float*)d_in[0];
  const float* mask   = (const float*)d_in[1];
  const float* qkv_w  = (const float*)d_in[2];
  const float* qkv_b  = (const float*)d_in[3];
  const float* proj_w = (const float*)d_in[4];
  const float* proj_b = (const float*)d_in[5];
  const float* rpb    = (const float*)d_in[6];
  const int*   rel_i  = (const int*)d_in[7];

  char* ws = (char*)d_ws;
  unsigned short* xb    = (unsigned short*)(ws);                 // 102,760,448 B (also attn out)
  unsigned short* qkvb  = (unsigned short*)(ws + 102760448);     // 308,281,344 B
  unsigned short* wqkv  = (unsigned short*)(ws + 411041792);     // 1,572,864 B
  unsigned short* wproj = (unsigned short*)(ws + 412614656);     // 524,288 B
  float*          bmb   = (float*)(ws + 413138944);              // 9,834,496 B

  (void)hipFuncSetAttribute(reinterpret_cast<const void*>(&k_gemm8<0>),
                            hipFuncAttributeMaxDynamicSharedMemorySize, 131072);
  (void)hipFuncSetAttribute(reinterpret_cast<const void*>(&k_gemm8<1>),
                            hipFuncAttributeMaxDynamicSharedMemorySize, 131072);

  k_cvt_x<<<2048, 256, 0, stream>>>(x, xb, MROWS * CDIM / 4);
  k_prep<<<512, 256, 0, stream>>>(qkv_w, proj_w, rpb, rel_i, mask, wqkv, wproj, bmb);
  // QKV GEMM: [100352,1536] = xb * wqkv^T + qkv_b  (bf16 out)
  k_gemm8<0><<<dim3(O_QKV/256, MROWS/256), 512, 131072, stream>>>(xb, wqkv, qkv_b, qkvb, O_QKV, CDIM);
  // attention (writes bf16 attn-out into xb region)
  k_attn<<<(B_TOT * NHEAD) / 4, 256, 0, stream>>>(qkvb, bmb, xb);
  // proj GEMM: out[100352,512] = xb * wproj^T + proj_b (f32 out)
  k_gemm8<1><<<dim3(CDIM/256, MROWS/256), 512, 131072, stream>>>(xb, wproj, proj_b, d_out, CDIM, CDIM);
}

// Round 3
// 505.242 us; speedup vs baseline: 1.4511x; 1.1619x over previous
//
#include <hip/hip_runtime.h>
#include <hip/hip_bf16.h>
#include <stdint.h>
#include <stddef.h>

// ---------------- problem constants ----------------
#define B_TOT   2048        // windows total
#define NTOK    49          // tokens per window
#define CDIM    512
#define NHEAD   16
#define HD      32
#define NWIN    64          // windows per image
#define MROWS   (B_TOT*NTOK)   // 100352
#define O_QKV   1536
#define SCALE_F 0.17677669529663687f   // 32^-0.5

typedef short bf16x8 __attribute__((ext_vector_type(8)));
typedef float f32x4  __attribute__((ext_vector_type(4)));

__device__ __forceinline__ unsigned short f2bf(float f){
  union { float f; unsigned u; } v; v.f = f;
  unsigned r = v.u + 0x7fffu + ((v.u >> 16) & 1u);
  return (unsigned short)(r >> 16);
}

#define GL16(g,l) __builtin_amdgcn_global_load_lds( \
      (const __attribute__((address_space(1))) unsigned int*)(g), \
      (__attribute__((address_space(3))) unsigned int*)(l), 16, 0, 0)

// ---------------- kernel 1: x fp32 -> bf16 ----------------
__global__ void k_cvt_x(const float* __restrict__ x, unsigned short* __restrict__ xb, int n4){
  int i = blockIdx.x * blockDim.x + threadIdx.x;
  int st = gridDim.x * blockDim.x;
  for (; i < n4; i += st){
    float4 v = ((const float4*)x)[i];
    uint2 o;
    o.x = (unsigned)f2bf(v.x) | ((unsigned)f2bf(v.y) << 16);
    o.y = (unsigned)f2bf(v.z) | ((unsigned)f2bf(v.w) << 16);
    ((uint2*)xb)[i] = o;
  }
}

// ---------------- kernel 2: weights -> bf16, fused bias+mask table ----------------
// bias table layout: bmb[(wi*16+h)][qt(49 rows)][kt(64 cols, kt>=49 -> -1e30)]
__global__ void k_prep(const float* __restrict__ qkv_w, const float* __restrict__ proj_w,
                       const float* __restrict__ rpb, const int* __restrict__ rel_idx,
                       const float* __restrict__ mask,
                       unsigned short* __restrict__ wqkv, unsigned short* __restrict__ wproj,
                       float* __restrict__ bmb){
  int i = blockIdx.x * blockDim.x + threadIdx.x;
  int st = gridDim.x * blockDim.x;
  for (int j = i; j < O_QKV*CDIM; j += st) wqkv[j] = f2bf(qkv_w[j]);
  for (int j = i; j < CDIM*CDIM;  j += st) wproj[j] = f2bf(proj_w[j]);
  const int TOT = NWIN * NHEAD * NTOK * 64;
  for (int j = i; j < TOT; j += st){
    int wh  = j / (NTOK*64);
    int rem = j - wh * (NTOK*64);
    int qt  = rem >> 6, kt = rem & 63;
    int wi = wh >> 4, h = wh & 15;
    float v;
    if (kt < NTOK){
      int rc = qt * NTOK + kt;
      v = mask[wi * (NTOK*NTOK) + rc] + rpb[rel_idx[rc] * NHEAD + h];
    } else v = -1e30f;
    bmb[j] = v;
  }
}

// ---------------- 8-phase 256x256 GEMM: C[M,N] = A[M,K]*B[N,K]^T + bias ----------------
#define LDA_(P,RG,MI,S) (*(const bf16x8*)(rA + (P)*32768 + (RG)*16384 + (MI)*2048 + ((S)?(cb0^64):cb0)))
#define LDB_(P,CG,NI,S) (*(const bf16x8*)(rB + (P)*32768 + (CG)*16384 + (NI)*2048 + ((S)?(cb0^64):cb0)))

#define STAGE_A(P,HG,KT) { \
    GL16(aS0 + (size_t)(HG)*64*Kb + (size_t)(KT)*128, ldA + (P)*32768 + (HG)*16384); \
    GL16(aS1 + (size_t)(HG)*64*Kb + (size_t)(KT)*128, ldA + (P)*32768 + (HG)*16384 + 8192); }
#define STAGE_B(P,HG,KT) { \
    GL16(bS0 + (size_t)(HG)*32*Kb + (size_t)(KT)*128, ldB + (P)*32768 + (HG)*16384); \
    GL16(bS1 + (size_t)(HG)*32*Kb + (size_t)(KT)*128, ldB + (P)*32768 + (HG)*16384 + 8192); }

#define PHASE(P,RG,CG,DOA,DOB,VM,...) { \
  if (DOA){ _Pragma("unroll") for (int mi=0;mi<4;++mi){ af[mi][0]=LDA_(P,RG,mi,0); af[mi][1]=LDA_(P,RG,mi,1);} } \
  if (DOB){ _Pragma("unroll") for (int ni=0;ni<2;++ni){ bf_[ni][0]=LDB_(P,CG,ni,0); bf_[ni][1]=LDB_(P,CG,ni,1);} } \
  __VA_ARGS__; \
  __builtin_amdgcn_s_barrier(); \
  asm volatile("s_waitcnt lgkmcnt(0)" ::: "memory"); \
  __builtin_amdgcn_sched_barrier(0); \
  __builtin_amdgcn_s_setprio(1); \
  _Pragma("unroll") for (int s=0;s<2;++s) \
    _Pragma("unroll") for (int mi=0;mi<4;++mi) \
      _Pragma("unroll") for (int ni=0;ni<2;++ni) \
        acc[(RG)*4+mi][(CG)*2+ni] = __builtin_amdgcn_mfma_f32_16x16x32_bf16(af[mi][s], bf_[ni][s], acc[(RG)*4+mi][(CG)*2+ni], 0,0,0); \
  __builtin_amdgcn_s_setprio(0); \
  if (VM) asm volatile("s_waitcnt vmcnt(4)" ::: "memory"); \
  __builtin_amdgcn_s_barrier(); \
  asm volatile("" ::: "memory"); \
}

template<int OUT_F32>
__global__ __launch_bounds__(512, 2) void k_gemm8(const unsigned short* __restrict__ Ag,
                                                  const unsigned short* __restrict__ Bg,
                                                  const float* __restrict__ bias,
                                                  void* __restrict__ Cout,
                                                  int Ndim, int Kdim){
  extern __shared__ char smem[];
  const int tid = threadIdx.x;
  const int wv = tid >> 6, lane = tid & 63, lg = lane >> 4, lr = lane & 15;
  const int wm = wv >> 2, wn = wv & 3;

  const int nbx = gridDim.x;
  const int nwg = nbx * gridDim.y;
  const int id  = blockIdx.y * nbx + blockIdx.x;
  const int nid = (id & 7) * (nwg >> 3) + (id >> 3);
  const int bx = nid % nbx, by = nid / nbx;
  const int bm0 = by * 256, bn0 = bx * 256;
  const size_t Kb = (size_t)Kdim * 2;
  const int NIT = Kdim >> 7;

  const int srow = tid >> 3;
  const int scb  = ((tid & 7) << 4) ^ ((srow & 7) << 4);
  const char* aS0 = (const char*)Ag + (size_t)(bm0 + srow) * Kb + scb;
  const char* aS1 = (const char*)Ag + (size_t)(bm0 + 128 + srow) * Kb + scb;
  const char* bS0 = (const char*)Bg + (size_t)(bn0 + (srow>>5)*64 + (srow&31)) * Kb + scb;
  const char* bS1 = (const char*)Bg + (size_t)(bn0 + 128 + (srow>>5)*64 + (srow&31)) * Kb + scb;
  char* ldA = smem + wv * 1024;
  char* ldB = smem + 65536 + wv * 1024;

  const int cb0 = (lg * 16) ^ ((lr & 7) << 4);
  const char* rA = smem + (wm*64 + lr) * 128;
  const char* rB = smem + 65536 + (wn*32 + lr) * 128;

  f32x4 acc[8][4];
  #pragma unroll
  for (int i = 0; i < 8; ++i)
    #pragma unroll
    for (int j = 0; j < 4; ++j)
      #pragma unroll
      for (int r = 0; r < 4; ++r) acc[i][j][r] = 0.f;

  bf16x8 af[4][2], bf_[2][2];

  STAGE_A(0,0,0); STAGE_A(0,1,0); STAGE_B(0,0,0); STAGE_B(0,1,0);
  STAGE_A(1,0,1); STAGE_B(1,1,1);
  asm volatile("s_waitcnt vmcnt(4)" ::: "memory");
  __builtin_amdgcn_s_barrier();
  asm volatile("" ::: "memory");

  for (int it = 0; it < NIT; ++it){
    const int T = 2*it;
    PHASE(0, 0,0, 1,1, 0, STAGE_A(1,1,(T+1)))
    PHASE(0, 0,1, 0,1, 0, STAGE_B(1,0,(T+1)))
    PHASE(0, 1,1, 1,0, 0, STAGE_A(0,0,(T+2)))
    PHASE(0, 1,0, 0,1, 1, STAGE_B(0,1,(T+2)))
    PHASE(1, 0,0, 1,1, 0, STAGE_A(0,1,(T+2)))
    PHASE(1, 0,1, 0,1, 0, STAGE_B(0,0,(T+2)))
    PHASE(1, 1,1, 1,0, 0, STAGE_A(1,0,(T+3)))
    PHASE(1, 1,0, 0,1, 1, STAGE_B(1,1,(T+3)))
  }

  #pragma unroll
  for (int RG = 0; RG < 2; ++RG)
    #pragma unroll
    for (int mi = 0; mi < 4; ++mi)
      #pragma unroll
      for (int CG = 0; CG < 2; ++CG)
        #pragma unroll
        for (int ni = 0; ni < 2; ++ni){
          f32x4 v = acc[RG*4+mi][CG*2+ni];
          const int col = bn0 + wn*64 + CG*32 + ni*16 + lr;
          const float bc = bias[col];
          #pragma unroll
          for (int r = 0; r < 4; ++r){
            const int row = bm0 + wm*128 + RG*64 + mi*16 + lg*4 + r;
            const float t = v[r] + bc;
            if (OUT_F32) ((float*)Cout)[(size_t)row * Ndim + col] = t;
            else ((unsigned short*)Cout)[(size_t)row * Ndim + col] = f2bf(t);
          }
        }
}

// ---------------- attention v2: swapped QK^T, LDS Vt, per-wave, no barriers ----------------
// one wave per (window, head). LDS per wave: Vt [32 d][128B] @0, P [64 qt][128B] @4096.
// Vt swizzle: byte(kt,d) = d*128 + (2*kt ^ (swzV(d)<<4)), swzV(d) = ((d&7)^(d>>3))&7
// P  swizzle: byte(qt,kt) = qt*128 + (2*kt ^ ((qt&7)<<4))
__global__ __launch_bounds__(256) void k_attn(const unsigned short* __restrict__ qkv,
                                              const float* __restrict__ bm,
                                              unsigned short* __restrict__ ao){
  __shared__ char lds[4][12288];
  const int wv = threadIdx.x >> 6, lane = threadIdx.x & 63;
  const int lg = lane >> 4, lr = lane & 15;
  const int gw = blockIdx.x * 4 + wv;
  const int w = gw >> 4, h = gw & 15, wi = w & (NWIN - 1);
  char* Vt = lds[wv];
  char* P  = lds[wv] + 4096;

  const unsigned short* base = qkv + (size_t)w * NTOK * O_QKV + h * HD;

  // --- issue V staging loads first (max MLP) ---
  const int vkt = lane >> 2, vch = lane & 3;     // kt = 16t+vkt, d-chunk = vch*8
  bf16x8 vld[4];
  #pragma unroll
  for (int t = 0; t < 4; ++t){
    int kt = 16*t + vkt; int kts = kt < NTOK ? kt : NTOK-1;
    vld[t] = *(const bf16x8*)(base + 1024 + (size_t)kts * O_QKV + vch * 8);
  }

  // --- Q/K fragments (direct from global, rows clamped) ---
  bf16x8 qf[4], kf[4];
  #pragma unroll
  for (int i = 0; i < 4; ++i){
    int t = 16*i + lr; int ts = t < NTOK ? t : NTOK-1;
    qf[i] = *(const bf16x8*)(base + (size_t)ts * O_QKV + lg*8);
    kf[i] = *(const bf16x8*)(base + 512 + (size_t)ts * O_QKV + lg*8);
  }

  // --- bias float4 loads: bias[mi][ni] = bm[qt][16ni+4lg .. +3], qt = 16mi+lr ---
  const float* bmp = bm + (size_t)(wi * NHEAD + h) * (NTOK * 64);
  f32x4 bias[4][4];
  #pragma unroll
  for (int mi = 0; mi < 4; ++mi){
    int qt = 16*mi + lr; int qtc = qt < NTOK ? qt : NTOK-1;
    #pragma unroll
    for (int ni = 0; ni < 4; ++ni)
      bias[mi][ni] = *(const f32x4*)(bmp + qtc*64 + ni*16 + lg*4);
  }

  // --- QK^T transposed: s2[ni][mi], lane holds P[qt=16mi+lr][kt=16ni+4lg+r] ---
  f32x4 z4 = {0.f, 0.f, 0.f, 0.f};
  f32x4 s2[4][4];
  #pragma unroll
  for (int ni = 0; ni < 4; ++ni)
    #pragma unroll
    for (int mi = 0; mi < 4; ++mi)
      s2[ni][mi] = __builtin_amdgcn_mfma_f32_16x16x32_bf16(kf[ni], qf[mi], z4, 0, 0, 0);

  // --- write V transposed into LDS (swizzled; conflict-free) ---
  #pragma unroll
  for (int t = 0; t < 4; ++t){
    int kt = 16*t + vkt;
    #pragma unroll
    for (int j = 0; j < 8; ++j){
      int d = vch*8 + j;
      int swz = ((d & 7) ^ (d >> 3)) & 7;
      int byte = d*128 + ((2*kt) ^ (swz << 4));
      *(unsigned short*)(Vt + byte) = (unsigned short)vld[t][j];
    }
  }

  // --- softmax per mi (lane owns row qt=16mi+lr), normalize, pack, write P ---
  #pragma unroll
  for (int mi = 0; mi < 4; ++mi){
    float v[4][4];
    float mx = -1e30f;
    #pragma unroll
    for (int ni = 0; ni < 4; ++ni)
      #pragma unroll
      for (int r = 0; r < 4; ++r){
        float t = s2[ni][mi][r] * SCALE_F + bias[mi][ni][r];
        v[ni][r] = t;
        mx = fmaxf(mx, t);
      }
    mx = fmaxf(mx, __shfl_xor(mx, 16));
    mx = fmaxf(mx, __shfl_xor(mx, 32));
    float sum = 0.f;
    #pragma unroll
    for (int ni = 0; ni < 4; ++ni)
      #pragma unroll
      for (int r = 0; r < 4; ++r){
        float p = __expf(v[ni][r] - mx);
        v[ni][r] = p;
        sum += p;
      }
    sum += __shfl_xor(sum, 16);
    sum += __shfl_xor(sum, 32);
    float rn = 1.0f / sum;
    const int qt = 16*mi + lr;
    #pragma unroll
    for (int ni = 0; ni < 4; ++ni){
      unsigned p0 = (unsigned)f2bf(v[ni][0]*rn) | ((unsigned)f2bf(v[ni][1]*rn) << 16);
      unsigned p1 = (unsigned)f2bf(v[ni][2]*rn) | ((unsigned)f2bf(v[ni][3]*rn) << 16);
      uint2 pw; pw.x = p0; pw.y = p1;
      int byte = qt*128 + ((32*ni + 8*lg) ^ ((lr & 7) << 4));
      *(uint2*)(P + byte) = pw;
    }
  }

  // --- PV: out[mi][ni] = sum_s mfma(P-frag, Vt-frag) ---
  f32x4 o[4][2];
  #pragma unroll
  for (int mi = 0; mi < 4; ++mi)
    #pragma unroll
    for (int ni = 0; ni < 2; ++ni)
      #pragma unroll
      for (int r = 0; r < 4; ++r) o[mi][ni][r] = 0.f;

  #pragma unroll
  for (int s = 0; s < 2; ++s){
    bf16x8 pf[4], vf[2];
    #pragma unroll
    for (int mi = 0; mi < 4; ++mi)
      pf[mi] = *(const bf16x8*)(P + (16*mi + lr)*128 + ((64*s + 16*lg) ^ ((lr & 7) << 4)));
    #pragma unroll
    for (int ni = 0; ni < 2; ++ni){
      int d = 16*ni + lr;
      int swz = ((d & 7) ^ (d >> 3)) & 7;
      vf[ni] = *(const bf16x8*)(Vt + d*128 + ((64*s + 16*lg) ^ (swz << 4)));
    }
    #pragma unroll
    for (int mi = 0; mi < 4; ++mi)
      #pragma unroll
      for (int ni = 0; ni < 2; ++ni)
        o[mi][ni] = __builtin_amdgcn_mfma_f32_16x16x32_bf16(pf[mi], vf[ni], o[mi][ni], 0, 0, 0);
  }

  // --- store (already normalized) ---
  unsigned short* aop = ao + (size_t)w * NTOK * CDIM + h * HD;
  #pragma unroll
  for (int mi = 0; mi < 4; ++mi)
    #pragma unroll
    for (int ni = 0; ni < 2; ++ni)
      #pragma unroll
      for (int r = 0; r < 4; ++r){
        int row = 16*mi + 4*lg + r, col = 16*ni + lr;
        if (row < NTOK)
          aop[(size_t)row * CDIM + col] = f2bf(o[mi][ni][r]);
      }
}

// ---------------- launcher ----------------
extern "C" void kernel_launch(void* const* d_in, const int* in_sizes, int n_in,
                              void* d_out, int out_size, void* d_ws, size_t ws_size,
                              hipStream_t stream){
  const float* x      = (const float*)d_in[0];
  const float* mask   = (const float*)d_in[1];
  const float* qkv_w  = (const float*)d_in[2];
  const float* qkv_b  = (const float*)d_in[3];
  const float* proj_w = (const float*)d_in[4];
  const float* proj_b = (const float*)d_in[5];
  const float* rpb    = (const float*)d_in[6];
  const int*   rel_i  = (const int*)d_in[7];

  char* ws = (char*)d_ws;
  unsigned short* xb    = (unsigned short*)(ws);                 // 102,760,448 B (also attn out)
  unsigned short* qkvb  = (unsigned short*)(ws + 102760448);     // 308,281,344 B
  unsigned short* wqkv  = (unsigned short*)(ws + 411041792);     // 1,572,864 B
  unsigned short* wproj = (unsigned short*)(ws + 412614656);     // 524,288 B
  float*          bmb   = (float*)(ws + 413138944);              // 64*16*49*64*4 = 12,845,056 B

  (void)hipFuncSetAttribute(reinterpret_cast<const void*>(&k_gemm8<0>),
                            hipFuncAttributeMaxDynamicSharedMemorySize, 131072);
  (void)hipFuncSetAttribute(reinterpret_cast<const void*>(&k_gemm8<1>),
                            hipFuncAttributeMaxDynamicSharedMemorySize, 131072);

  k_cvt_x<<<2048, 256, 0, stream>>>(x, xb, MROWS * CDIM / 4);
  k_prep<<<512, 256, 0, stream>>>(qkv_w, proj_w, rpb, rel_i, mask, wqkv, wproj, bmb);
  k_gemm8<0><<<dim3(O_QKV/256, MROWS/256), 512, 131072, stream>>>(xb, wqkv, qkv_b, qkvb, O_QKV, CDIM);
  k_attn<<<(B_TOT * NHEAD) / 4, 256, 0, stream>>>(qkvb, bmb, xb);
  k_gemm8<1><<<dim3(CDIM/256, MROWS/256), 512, 131072, stream>>>(xb, wproj, proj_b, d_out, CDIM, CDIM);
}